// Round 10
// baseline (217.879 us; speedup 1.0000x reference)
//
#include <hip/hip_runtime.h>

#define B_ 32
#define N_ 8732
#define N2_ 17464
#define N4_ 4366      // N2_/4 exactly
#define C_ 21
#define NCLS 20
#define K_ 200
#define NITEMS 640    // B_*NCLS
#define PGRID 512     // persistent grid: exactly 2 blocks/CU on 256 CUs
#define CONF_T 0.01f
#define NMS_T 0.45f
#define TPB_S 256
#define TPB_N 512
#define POOL 1024
#define RANKCAP 512   // refine-descent target (fallback refine path)
#define HB0 2048      // level-0 bins (shift 15)
#define HB 1024       // refine-level bins (shift 5 then 0)
#define BIN0 30791u   // 0x3C23D70B >> 15: bin offset for level 0

typedef unsigned long long u64;
typedef unsigned int u32;

// ---------------------------------------------------------------------------
// Kernel 1 (round-6 hardware-verified): softmax over C=21. Coalesced
// float4->LDS staging, per-row compute in registers, DIRECT global dword
// stores per class plane. Also zeroes the work-steal counter (one thread;
// stream order makes it visible to nms_kernel). Grid: (ceil(N/256), B, 2).
// ---------------------------------------------------------------------------
__global__ __launch_bounds__(TPB_S) void softmax_kernel(
    const float* __restrict__ conf1, const float* __restrict__ conf2,
    float* __restrict__ scores, u32* gcnt)
{
  __shared__ float lds[TPB_S * C_];   // 21 KB
  const int t = threadIdx.x;
  const int tile = blockIdx.x * TPB_S;
  const int b = blockIdx.y;
  const int view = blockIdx.z;
  if (gcnt && t == 0 && tile == 0 && b == 0 && view == 0) *gcnt = 0u;
  int cnt = N_ - tile; if (cnt > TPB_S) cnt = TPB_S;   // 256 or 28 (both %4==0)
  const float* conf = view ? conf2 : conf1;
  const float4* src = (const float4*)(conf + ((size_t)b * N_ + tile) * C_);  // 16B-aligned
  float4* l4 = (float4*)lds;
  const int n4 = (cnt * C_) >> 2;
  for (int i = t; i < n4; i += TPB_S) l4[i] = src[i];
  __syncthreads();
  if (t < cnt) {
    float x[C_];
#pragma unroll
    for (int i = 0; i < C_; ++i) x[i] = lds[t * C_ + i];  // stride-21: 2-way, free
    float m = x[0];
#pragma unroll
    for (int i = 1; i < C_; ++i) m = fmaxf(m, x[i]);
    float e[C_];
    float sum = 0.0f;
#pragma unroll
    for (int i = 0; i < C_; ++i) { e[i] = __expf(x[i] - m); sum += e[i]; }
    float inv = 1.0f / sum;   // one IEEE div, not 20
    float* o = scores + ((size_t)b * NCLS) * N2_ + (size_t)view * N_ + (tile + t);
#pragma unroll
    for (int c = 1; c < C_; ++c) { *o = e[c] * inv; o += N2_; }
  }
}

// ---------------------------------------------------------------------------
// Kernel 2: per-(image,class) item, ROUND-8 HARDWARE-VERIFIED phase code
// (shift-15 histogram -> suffix sums -> bin select -> [rare refine] ->
// ballot-collect -> b128 all-pairs rank -> decode -> triangle IoU ->
// word-chunked static scan -> in-wave compact), wrapped in a WORK-STEALING
// loop: 512 persistent blocks (exactly 2/CU) process static items 0..511,
// then steal items 512..639 via a global counter — removes the 2.5-blocks/CU
// tail quantization of the 640-block grid (wall was ~3x per-block latency).
// If gcnt == nullptr (workspace too small), grid is 640 and each block does
// exactly its one item (round-8 behavior).
// ---------------------------------------------------------------------------
__global__ __launch_bounds__(TPB_N, 2) void nms_kernel(
    const float* __restrict__ scores,
    const float4* __restrict__ loc1,
    const float4* __restrict__ loc2,
    const float4* __restrict__ dbox,
    float* __restrict__ out, u32* gcnt)
{
  const int t = threadIdx.x;
  const int lane = t & 63;
  const int wv = t >> 6;

  __shared__ u32 hist[HB0];              // 8 KB (L0: 2048 @shift15; refine: first 1024)
  __shared__ u64 pool[POOL] __attribute__((aligned(16)));  // 8 KB, pre-zeroed
  __shared__ u64 spool[256];             // 2 KB, rank-ordered top-200
  __shared__ float4 bb[K_];              // 3.2 KB
  __shared__ float bar[K_];
  __shared__ u64 rowmask[K_][4];         // 6.4 KB (triangle: row j has cols>j)
  __shared__ u64 validmask[4];
  __shared__ u32 wtot[8];
  __shared__ u32 sh_sel, sh_Sb, sh_Sn, sh_nc, sh_item;

  u32 item = blockIdx.x;

  while (true) {
    const int bimg = (int)(item / NCLS);
    const int cls = 1 + (int)(item % NCLS);
    const float4* sc4 = (const float4*)(scores + ((size_t)bimg * NCLS + (cls - 1)) * N2_);
    float* ob = out + ((size_t)bimg * C_ + cls) * K_ * 5;

    // ---- fused output zeroing (replaces hipMemsetAsync) ----
    {
      const float4 z4 = make_float4(0.f, 0.f, 0.f, 0.f);
      if (t < 250) ((float4*)ob)[t] = z4;                      // own (b,cls) slice
      if (cls == 1 && t >= 256 && t < 506)                     // background class 0
        ((float4*)(out + (size_t)bimg * C_ * K_ * 5))[t - 256] = z4;
    }

    // ---- load this item's 17464 scores into registers: the ONLY global pass ----
    float4 v[9];
#pragma unroll
    for (int k = 0; k < 9; ++k) {
      int i = t + k * TPB_N;
      v[k] = (i < N4_) ? sc4[i] : make_float4(0.f, 0.f, 0.f, 0.f);
    }

    // ---- zero L0 hist (2048) + whole pool (unconditional b128 rank) ----
    hist[t] = 0u; hist[t + 512] = 0u; hist[t + 1024] = 0u; hist[t + 1536] = 0u;
    pool[t] = 0ULL; pool[t + TPB_N] = 0ULL;
    if (t == 0) sh_nc = 0u;
    __syncthreads();

    // ---- level 0: 2048-bin histogram at shift 15 ----
    // valid keys 0x3C23D70B..0x3F800000 -> (key>>15)-30791 in [0,1721]
#pragma unroll
    for (int k = 0; k < 9; ++k) {
      float ss[4] = {v[k].x, v[k].y, v[k].z, v[k].w};
#pragma unroll
      for (int c2 = 0; c2 < 4; ++c2) {
        float s = ss[c2];
        if (s > CONF_T)
          atomicAdd(&hist[(__float_as_uint(s) >> 15) - BIN0], 1u);
      }
    }
    __syncthreads();

    // ---- suffix sums over 2048 bins: 4 bins/thread + wave scan ----
    {
      u32 c0 = hist[4 * t + 0], c1 = hist[4 * t + 1];
      u32 c2b = hist[4 * t + 2], c3 = hist[4 * t + 3];
      u32 T = c0 + c1 + c2b + c3;
      u32 x = T;
#pragma unroll
      for (int off = 1; off < 64; off <<= 1) {
        u32 y = __shfl_down(x, off);
        if (lane + off < 64) x += y;
      }                                   // x = suffix-incl sum of thread totals in wave
      if (lane == 0) wtot[wv] = x;
      __syncthreads();
      u32 wafter = 0;
      for (int w = wv + 1; w < 8; ++w) wafter += wtot[w];
      u32 after_me = (x - T) + wafter;    // totals of threads strictly after t
      u32 S3 = c3 + after_me, S2 = c2b + S3, S1 = c1 + S2, S0 = c0 + S1;
      hist[4 * t + 0] = S0; hist[4 * t + 1] = S1;
      hist[4 * t + 2] = S2; hist[4 * t + 3] = S3;
    }
    __syncthreads();

    u32 loKey, prefix = 0, Gacc = 0;
    bool needMore = false;
    {
      u32 total = hist[0];                // block-uniform
      if (total < (u32)K_) {
        loKey = 1u;                       // undershoot: take all valid (<200)
      } else {
        for (int h = t; h < HB0; h += TPB_N) {
          u32 Sb = hist[h];
          u32 Sn = (h + 1 < HB0) ? hist[h + 1] : 0u;
          if (Sb >= (u32)K_ && Sn < (u32)K_) { sh_sel = (u32)h; sh_Sb = Sb; sh_Sn = Sn; }
        }
        __syncthreads();                  // uniform branch: total is block-uniform
        prefix = sh_sel + BIN0;           // real key>>15 value
        loKey = prefix << 15;
        Gacc = sh_Sn;
        needMore = sh_Sb > (u32)RANKCAP;  // rare: one 32768-key window holding >312
      }
    }

    // ---- refine levels (rare): shift 5 (1024 bins) then shift 0 (32 bins) ----
    for (int lvl = 1; lvl <= 2 && needMore; ++lvl) {
      const int shift = (lvl == 1) ? 5 : 0;
      const int mshift = (lvl == 1) ? 15 : 5;
      const u32 bmask = (lvl == 1) ? 1023u : 31u;
      for (int h = t; h < HB; h += TPB_N) hist[h] = 0u;
      __syncthreads();
#pragma unroll
      for (int k = 0; k < 9; ++k) {
        float ss[4] = {v[k].x, v[k].y, v[k].z, v[k].w};
#pragma unroll
        for (int c2 = 0; c2 < 4; ++c2) {
          float s = ss[c2];
          if (s > CONF_T) {
            u32 key = __float_as_uint(s);
            if ((key >> mshift) == prefix)
              atomicAdd(&hist[(key >> shift) & bmask], 1u);
          }
        }
      }
      __syncthreads();
      // suffix sums over 1024 bins: 2 bins/thread + wave scan
      u32 c0 = hist[2 * t], c1 = hist[2 * t + 1];
      u32 T = c0 + c1;
      u32 x = T;
#pragma unroll
      for (int off = 1; off < 64; off <<= 1) {
        u32 y = __shfl_down(x, off);
        if (lane + off < 64) x += y;
      }
      if (lane == 0) wtot[wv] = x;
      __syncthreads();
      u32 wafter = 0;
      for (int w = wv + 1; w < 8; ++w) wafter += wtot[w];
      u32 after_me = (x - T) + wafter;
      u32 S1 = c1 + after_me, S0 = c0 + S1;
      hist[2 * t] = S0; hist[2 * t + 1] = S1;
      __syncthreads();
      u32 need = (u32)K_ - Gacc;
      for (int h = t; h < HB; h += TPB_N) {
        u32 Sb = hist[h];
        u32 Sn2 = (h + 1 < HB) ? hist[h + 1] : 0u;
        if (Sb >= need && Sn2 < need) { sh_sel = (u32)h; sh_Sb = Sb; sh_Sn = Sn2; }
      }
      __syncthreads();
      prefix = (prefix << ((lvl == 1) ? 10 : 5)) | sh_sel;
      u32 candTotal = Gacc + sh_Sb;
      Gacc += sh_Sn;
      loKey = prefix << shift;
      needMore = (candTotal > (u32)RANKCAP) && (lvl < 2);
    }

    // ---- ballot-collect candidates (key >= loKey) into pool, 1 atomic/wave ----
#pragma unroll
    for (int k = 0; k < 9; ++k) {
      int i = t + k * TPB_N;
      float ss[4] = {v[k].x, v[k].y, v[k].z, v[k].w};
#pragma unroll
      for (int c2 = 0; c2 < 4; ++c2) {
        float s = ss[c2];
        u32 key = __float_as_uint(s);
        bool pred = (s > CONF_T) && (key >= loKey);
        u64 bal = __ballot(pred);
        if (bal) {
          u32 wb = 0;
          if (lane == 0) wb = atomicAdd(&sh_nc, (u32)__popcll(bal));
          wb = __shfl(wb, 0);
          if (pred) {
            u32 pos = wb + (u32)__popcll(bal & ((1ULL << lane) - 1ULL));
            if (pos < (u32)POOL)
              pool[pos] = ((u64)key << 32) | (u64)(0xFFFFFFFFu - (u32)(i * 4 + c2));
          }
        }
      }
    }
    __syncthreads();

    // ---- rank-by-counting: composite keys unique -> rank = #{keys > mine} ----
    // pool pre-zeroed, so b128 reads past nc compare against 0 (harmless).
    u32 nc = sh_nc < (u32)POOL ? sh_nc : (u32)POOL;
    if (t < 256) spool[t] = 0ULL;
    const bool dual = nc > (u32)TPB_N;    // block-uniform; rare (lvl-2 exit >512)
    u64 my0 = (t < (int)nc) ? pool[t] : 0ULL;
    u64 my1 = (dual && t + TPB_N < (int)nc) ? pool[t + TPB_N] : 0ULL;
    __syncthreads();
    u32 r0 = 0, r1 = 0;
    if ((u32)(t & ~63) < nc) {            // whole waves past nc skip the loop
      if (!dual) {
#pragma unroll 4
        for (u32 k = 0; k < nc; k += 2) { // 2 keys per ds_read_b128
          ulonglong2 pk = *(const ulonglong2*)&pool[k];
          r0 += (pk.x > my0) ? 1u : 0u;
          r0 += (pk.y > my0) ? 1u : 0u;
        }
      } else {
#pragma unroll 4
        for (u32 k = 0; k < nc; k += 2) {
          ulonglong2 pk = *(const ulonglong2*)&pool[k];
          r0 += (pk.x > my0) ? 1u : 0u;
          r0 += (pk.y > my0) ? 1u : 0u;
          r1 += (pk.x > my1) ? 1u : 0u;
          r1 += (pk.y > my1) ? 1u : 0u;
        }
      }
    }
    if (my0 != 0ULL && r0 < (u32)K_) spool[r0] = my0;
    if (dual && my1 != 0ULL && r1 < (u32)K_) spool[r1] = my1;
    __syncthreads();
    // spool[0..199] == exact top_k (desc score, ties by ascending index)

    // ---- decode boxes for top-200; idle threads 256+ zero rowmask ----
    float scv = 0.f;
    if (t < K_) {
      float x1 = 0.f, y1 = 0.f, x2 = 0.f, y2 = 0.f, area = 0.f;
      u64 e = spool[t];
      u32 kb = (u32)(e >> 32);
      if (kb != 0u) {
        scv = __uint_as_float(kb);
        u32 idx = 0xFFFFFFFFu - (u32)(e & 0xFFFFFFFFu);
        int nn = (idx < (u32)N_) ? (int)idx : (int)(idx - N_);
        float4 l = (idx < (u32)N_) ? loc1[(size_t)bimg * N_ + nn]
                                   : loc2[(size_t)bimg * N_ + nn];
        float4 d = dbox[nn];
        float cx = d.x + l.x * 0.1f * d.z;
        float cy = d.y + l.y * 0.1f * d.w;
        float w = d.z * __expf(l.z * 0.2f);
        float h = d.w * __expf(l.w * 0.2f);
        x1 = cx - w * 0.5f; y1 = cy - h * 0.5f;
        x2 = cx + w * 0.5f; y2 = cy + h * 0.5f;
        if (idx >= (u32)N_) {   // horizontal flip of second (TTA) view
          float tmp = 1.0f - x2; x2 = 1.0f - x1; x1 = tmp;
        }
        area = (x2 - x1) * (y2 - y1);
      }
      bb[t] = make_float4(x1, y1, x2, y2);
      bar[t] = area;
    } else if (t >= 256) {
      for (int i = t - 256; i < 4 * K_; i += 256) ((u64*)rowmask)[i] = 0ULL;
    }
    {
      bool myvalid = (t < K_) && (scv > CONF_T);
      u64 bal = __ballot(myvalid);
      if (lane == 0 && wv < 4) validmask[wv] = bal;
    }
    __syncthreads();

    // ---- triangle IoU: row j, cols j+1..199, split across 400 threads ----
    if (t < 2 * K_) {
      const int j = (t < K_) ? t : (t - K_);
      const int h = (t < K_) ? 0 : 1;
      const int L = K_ - 1 - j;             // #cols after j
      const int half = (L + 1) >> 1;
      const int s0c = j + 1 + (h ? half : 0);
      const int e0c = h ? K_ : (j + 1 + half);
      if (s0c < e0c) {
        float4 mb = bb[j];
        float ma = bar[j];
        for (int w = (s0c >> 6); w <= ((e0c - 1) >> 6); ++w) {
          int ka = (w << 6) > s0c ? (w << 6) : s0c;
          int kb2 = ((w + 1) << 6) < e0c ? ((w + 1) << 6) : e0c;
          u64 m = 0ULL;
          for (int k2 = ka; k2 < kb2; ++k2) {
            float4 obx = bb[k2];
            float ox1 = fmaxf(mb.x, obx.x);
            float oy1 = fmaxf(mb.y, obx.y);
            float ox2 = fminf(mb.z, obx.z);
            float oy2 = fminf(mb.w, obx.w);
            float inter = fmaxf(ox2 - ox1, 0.f) * fmaxf(oy2 - oy1, 0.f);
            float uni = ma + bar[k2] - inter;
            m |= (inter > NMS_T * uni) ? (1ULL << (k2 & 63)) : 0ULL;
          }
          if (m) atomicOr(&rowmask[j][w], m);
        }
      }
    }
    __syncthreads();
    // waves 1-7 wait at the steal barrier; wave 0 finishes the item alone.

    // ---- static pipelined greedy scan, chunked by word, then compact ----
    if (t < 64) {
      const u64 vv0 = validmask[0], vv1 = validmask[1];
      const u64 vv2 = validmask[2], vv3 = validmask[3];
      u64 s0 = 0, s1 = 0, s2 = 0, s3 = 0;
      u64 k0 = 0, k1 = 0, k2m = 0, k3 = 0;
#pragma unroll 8
      for (int j = 0; j < 64; ++j) {
        u64 q0 = rowmask[j][0], q1 = rowmask[j][1], q2 = rowmask[j][2], q3 = rowmask[j][3];
        u64 bit = 1ULL << j;
        if ((vv0 & bit) && !(s0 & bit)) { s0 |= q0; s1 |= q1; s2 |= q2; s3 |= q3; k0 |= bit; }
      }
#pragma unroll 8
      for (int j = 64; j < 128; ++j) {
        u64 q1 = rowmask[j][1], q2 = rowmask[j][2], q3 = rowmask[j][3];
        u64 bit = 1ULL << (j & 63);
        if ((vv1 & bit) && !(s1 & bit)) { s1 |= q1; s2 |= q2; s3 |= q3; k1 |= bit; }
      }
#pragma unroll 8
      for (int j = 128; j < 192; ++j) {
        u64 q2 = rowmask[j][2], q3 = rowmask[j][3];
        u64 bit = 1ULL << (j & 63);
        if ((vv2 & bit) && !(s2 & bit)) { s2 |= q2; s3 |= q3; k2m |= bit; }
      }
#pragma unroll
      for (int j = 192; j < K_; ++j) {
        u64 q3 = rowmask[j][3];
        u64 bit = 1ULL << (j & 63);
        if ((vv3 & bit) && !(s3 & bit)) { s3 |= q3; k3 |= bit; }
      }
      // ---- compact kept entries (lane-parallel within wave 0) ----
      const u32 n0 = (u32)__popcll(k0);
      const u32 n01 = n0 + (u32)__popcll(k1);
      const u32 n012 = n01 + (u32)__popcll(k2m);
      const u64 below = (1ULL << lane) - 1ULL;
#pragma unroll
      for (int w = 0; w < 4; ++w) {
        int j = (w << 6) + lane;
        if (j < K_) {
          u64 kw = (w == 0) ? k0 : (w == 1) ? k1 : (w == 2) ? k2m : k3;
          if ((kw >> lane) & 1ULL) {
            int pos2 = (int)__popcll(kw & below)
                    + (int)((w == 0) ? 0u : (w == 1) ? n0 : (w == 2) ? n01 : n012);
            u64 e = spool[j];
            float sc = __uint_as_float((u32)(e >> 32));
            float4 bx = bb[j];
            float* o = ob + (size_t)pos2 * 5;
            o[0] = sc; o[1] = bx.x; o[2] = bx.y; o[3] = bx.z; o[4] = bx.w;
          }
        }
      }
    }

    // ---- steal next item (or exit) ----
    if (t == 0)
      sh_item = gcnt ? ((u32)PGRID + atomicAdd(gcnt, 1u)) : 0xFFFFFFFFu;
    __syncthreads();   // also protects LDS reuse across iterations
    item = sh_item;
    if (item >= (u32)NITEMS) break;
  }
}

extern "C" void kernel_launch(void* const* d_in, const int* in_sizes, int n_in,
                              void* d_out, int out_size, void* d_ws, size_t ws_size,
                              hipStream_t stream) {
  const float* loc1 = (const float*)d_in[0];
  const float* conf1 = (const float*)d_in[1];
  const float* loc2 = (const float*)d_in[2];
  const float* conf2 = (const float*)d_in[3];
  const float* dbox = (const float*)d_in[4];
  float* out = (float*)d_out;
  float* scores = (float*)d_ws;   // [B, NCLS, 2N] fp32 = 44.7 MB

  const size_t SCORES_BYTES = (size_t)B_ * NCLS * N2_ * sizeof(float);
  u32* gcnt = nullptr;
  int grid = NITEMS;               // fallback: one block per item (round-8 mode)
  if (ws_size >= SCORES_BYTES + sizeof(u32)) {
    gcnt = (u32*)((char*)d_ws + SCORES_BYTES);   // 16B-aligned (SCORES_BYTES%16==0)
    grid = PGRID;                  // persistent: exactly 2 blocks/CU, work-stealing
  }

  dim3 g1((N_ + TPB_S - 1) / TPB_S, B_, 2);
  softmax_kernel<<<g1, TPB_S, 0, stream>>>(conf1, conf2, scores, gcnt);

  nms_kernel<<<grid, TPB_N, 0, stream>>>(
      scores, (const float4*)loc1, (const float4*)loc2, (const float4*)dbox,
      out, gcnt);
}

// Round 11
// 150.715 us; speedup vs baseline: 1.4456x; 1.4456x over previous
//
#include <hip/hip_runtime.h>

#define B_ 32
#define N_ 8732
#define N2_ 17464
#define N4_ 4366      // N2_/4 exactly
#define C_ 21
#define NCLS 20
#define K_ 200
#define CONF_T 0.01f
#define NMS_T 0.45f
#define TPB_S 256
#define TPB_N 512
#define POOL 1024
#define RANKCAP 512   // refine-descent target (fallback refine path)
#define HB0 2048      // level-0 bins (shift 15)
#define HB 1024       // refine-level bins (shift 5 then 0)
#define BIN0 30791u   // 0x3C23D70B >> 15: bin offset for level 0

typedef unsigned long long u64;
typedef unsigned int u32;

// ---------------------------------------------------------------------------
// Kernel 1 (round-6 hardware-verified, unchanged): softmax over C=21.
// Coalesced float4->LDS staging, per-row compute in registers, DIRECT global
// dword stores per class plane. Grid: (ceil(N/256), B, 2 views).
// ---------------------------------------------------------------------------
__global__ __launch_bounds__(TPB_S) void softmax_kernel(
    const float* __restrict__ conf1, const float* __restrict__ conf2,
    float* __restrict__ scores)
{
  __shared__ float lds[TPB_S * C_];   // 21 KB
  const int t = threadIdx.x;
  const int tile = blockIdx.x * TPB_S;
  const int b = blockIdx.y;
  const int view = blockIdx.z;
  int cnt = N_ - tile; if (cnt > TPB_S) cnt = TPB_S;   // 256 or 28 (both %4==0)
  const float* conf = view ? conf2 : conf1;
  const float4* src = (const float4*)(conf + ((size_t)b * N_ + tile) * C_);  // 16B-aligned
  float4* l4 = (float4*)lds;
  const int n4 = (cnt * C_) >> 2;
  for (int i = t; i < n4; i += TPB_S) l4[i] = src[i];
  __syncthreads();
  if (t < cnt) {
    float x[C_];
#pragma unroll
    for (int i = 0; i < C_; ++i) x[i] = lds[t * C_ + i];  // stride-21: 2-way, free
    float m = x[0];
#pragma unroll
    for (int i = 1; i < C_; ++i) m = fmaxf(m, x[i]);
    float e[C_];
    float sum = 0.0f;
#pragma unroll
    for (int i = 0; i < C_; ++i) { e[i] = __expf(x[i] - m); sum += e[i]; }
    float inv = 1.0f / sum;   // one IEEE div, not 20
    float* o = scores + ((size_t)b * NCLS) * N2_ + (size_t)view * N_ + (tile + t);
#pragma unroll
    for (int c = 1; c < C_; ++c) { *o = e[c] * inv; o += N2_; }
  }
}

// ---------------------------------------------------------------------------
// Kernel 2: per-(image,class), round-8 verified structure with three
// contained edits: (1) bin-selection FUSED into the suffix-scan phase (each
// thread holds S0..S3 and S4=after_me, so every adjacent bin pair (h,h+1) is
// checked inline -> no S-writeback, no 2048-bin rescan, one fewer barrier);
// (2) collect via count -> block scan -> per-thread writes (pool order is
// irrelevant: composite keys unique -> rank-by-counting is order-invariant);
// (3) spool zeroed in the top zero phase. Everything else verbatim round 8.
// One 512-thread block per (b, c); grid 640 (all blocks co-resident).
// ---------------------------------------------------------------------------
__global__ __launch_bounds__(TPB_N, 2) void nms_kernel(
    const float* __restrict__ scores,
    const float4* __restrict__ loc1,
    const float4* __restrict__ loc2,
    const float4* __restrict__ dbox,
    float* __restrict__ out)
{
  const int t = threadIdx.x;
  const int lane = t & 63;
  const int wv = t >> 6;
  const int bimg = blockIdx.x / NCLS;
  const int cls = 1 + (blockIdx.x % NCLS);
  const float4* sc4 = (const float4*)(scores + ((size_t)bimg * NCLS + (cls - 1)) * N2_);
  float* ob = out + ((size_t)bimg * C_ + cls) * K_ * 5;

  __shared__ u32 hist[HB0];              // 8 KB (L0: 2048 @shift15; refine: first 1024)
  __shared__ u64 pool[POOL] __attribute__((aligned(16)));  // 8 KB, pre-zeroed
  __shared__ u64 spool[256];             // 2 KB, rank-ordered top-200
  __shared__ float4 bb[K_];              // 3.2 KB
  __shared__ float bar[K_];
  __shared__ u64 rowmask[K_][4];         // 6.4 KB (triangle: row j has cols>j)
  __shared__ u64 validmask[4];
  __shared__ u32 wtot[8];
  __shared__ u32 sh_sel, sh_Sb, sh_Sn, sh_nc, sh_total;

  // ---- fused output zeroing (replaces hipMemsetAsync) ----
  {
    const float4 z4 = make_float4(0.f, 0.f, 0.f, 0.f);
    if (t < 250) ((float4*)ob)[t] = z4;                      // own (b,cls) slice
    if (cls == 1 && t >= 256 && t < 506)                     // background class 0
      ((float4*)(out + (size_t)bimg * C_ * K_ * 5))[t - 256] = z4;
  }

  // ---- load this (b,c)'s 17464 scores into registers: the ONLY global pass ----
  float4 v[9];
#pragma unroll
  for (int k = 0; k < 9; ++k) {
    int i = t + k * TPB_N;
    v[k] = (i < N4_) ? sc4[i] : make_float4(0.f, 0.f, 0.f, 0.f);
  }

  // ---- zero L0 hist (2048) + pool + spool ----
  hist[t] = 0u; hist[t + 512] = 0u; hist[t + 1024] = 0u; hist[t + 1536] = 0u;
  pool[t] = 0ULL; pool[t + TPB_N] = 0ULL;
  if (t < 256) spool[t] = 0ULL;
  __syncthreads();

  // ---- level 0: 2048-bin histogram at shift 15 ----
  // valid keys 0x3C23D70B..0x3F800000 -> (key>>15)-30791 in [0,1721]
#pragma unroll
  for (int k = 0; k < 9; ++k) {
    float ss[4] = {v[k].x, v[k].y, v[k].z, v[k].w};
#pragma unroll
    for (int c2 = 0; c2 < 4; ++c2) {
      float s = ss[c2];
      if (s > CONF_T)
        atomicAdd(&hist[(__float_as_uint(s) >> 15) - BIN0], 1u);
    }
  }
  __syncthreads();

  // ---- suffix sums over 2048 bins + FUSED bin select ----
  // Thread t owns bins 4t..4t+3 with suffix sums S0..S3; S4 = after_me is
  // the suffix of bin 4t+4 (wafter for lane 63 bridges waves; 0 at the end).
  // Every adjacent pair (h,h+1) is therefore checked by exactly one thread.
  {
    u32 c0 = hist[4 * t + 0], c1 = hist[4 * t + 1];
    u32 c2b = hist[4 * t + 2], c3 = hist[4 * t + 3];
    u32 T = c0 + c1 + c2b + c3;
    u32 x = T;
#pragma unroll
    for (int off = 1; off < 64; off <<= 1) {
      u32 y = __shfl_down(x, off);
      if (lane + off < 64) x += y;
    }                                   // x = suffix-incl sum of thread totals in wave
    if (lane == 0) wtot[wv] = x;
    __syncthreads();
    u32 wafter = 0;
    for (int w = wv + 1; w < 8; ++w) wafter += wtot[w];
    u32 after_me = (x - T) + wafter;    // totals of threads strictly after t
    u32 S4 = after_me;
    u32 S3 = c3 + S4, S2 = c2b + S3, S1 = c1 + S2, S0 = c0 + S1;
    if (t == 0) sh_total = S0;          // total valid count
    if (S0 >= (u32)K_ && S1 < (u32)K_) { sh_sel = 4u * t + 0u; sh_Sb = S0; sh_Sn = S1; }
    if (S1 >= (u32)K_ && S2 < (u32)K_) { sh_sel = 4u * t + 1u; sh_Sb = S1; sh_Sn = S2; }
    if (S2 >= (u32)K_ && S3 < (u32)K_) { sh_sel = 4u * t + 2u; sh_Sb = S2; sh_Sn = S3; }
    if (S3 >= (u32)K_ && S4 < (u32)K_) { sh_sel = 4u * t + 3u; sh_Sb = S3; sh_Sn = S4; }
  }
  __syncthreads();

  u32 loKey, prefix = 0, Gacc = 0;
  bool needMore = false;
  {
    u32 total = sh_total;               // block-uniform
    if (total < (u32)K_) {
      loKey = 1u;                       // undershoot: take all valid (<200)
    } else {
      prefix = sh_sel + BIN0;           // real key>>15 value
      loKey = prefix << 15;
      Gacc = sh_Sn;
      needMore = sh_Sb > (u32)RANKCAP;  // rare: one 32768-key window holding >312
    }
  }

  // ---- refine levels (rare): shift 5 (1024 bins) then shift 0 (32 bins) ----
  for (int lvl = 1; lvl <= 2 && needMore; ++lvl) {
    const int shift = (lvl == 1) ? 5 : 0;
    const int mshift = (lvl == 1) ? 15 : 5;
    const u32 bmask = (lvl == 1) ? 1023u : 31u;
    for (int h = t; h < HB; h += TPB_N) hist[h] = 0u;
    __syncthreads();
#pragma unroll
    for (int k = 0; k < 9; ++k) {
      float ss[4] = {v[k].x, v[k].y, v[k].z, v[k].w};
#pragma unroll
      for (int c2 = 0; c2 < 4; ++c2) {
        float s = ss[c2];
        if (s > CONF_T) {
          u32 key = __float_as_uint(s);
          if ((key >> mshift) == prefix)
            atomicAdd(&hist[(key >> shift) & bmask], 1u);
        }
      }
    }
    __syncthreads();
    // suffix sums over 1024 bins: 2 bins/thread + wave scan
    u32 c0 = hist[2 * t], c1 = hist[2 * t + 1];
    u32 T = c0 + c1;
    u32 x = T;
#pragma unroll
    for (int off = 1; off < 64; off <<= 1) {
      u32 y = __shfl_down(x, off);
      if (lane + off < 64) x += y;
    }
    if (lane == 0) wtot[wv] = x;
    __syncthreads();
    u32 wafter = 0;
    for (int w = wv + 1; w < 8; ++w) wafter += wtot[w];
    u32 after_me = (x - T) + wafter;
    u32 S2 = after_me;
    u32 S1 = c1 + S2, S0 = c0 + S1;
    u32 need = (u32)K_ - Gacc;
    if (S0 >= need && S1 < need) { sh_sel = 2u * t + 0u; sh_Sb = S0; sh_Sn = S1; }
    if (S1 >= need && S2 < need) { sh_sel = 2u * t + 1u; sh_Sb = S1; sh_Sn = S2; }
    __syncthreads();
    prefix = (prefix << ((lvl == 1) ? 10 : 5)) | sh_sel;
    u32 candTotal = Gacc + sh_Sb;
    Gacc += sh_Sn;
    loKey = prefix << shift;
    needMore = (candTotal > (u32)RANKCAP) && (lvl < 2);
  }

  // ---- collect: count -> block scan -> per-thread sequential writes ----
  // (pool order is irrelevant: keys unique -> rank-by-counting invariant)
  {
    u32 mycnt = 0;
#pragma unroll
    for (int k = 0; k < 9; ++k) {
      float ss[4] = {v[k].x, v[k].y, v[k].z, v[k].w};
#pragma unroll
      for (int c2 = 0; c2 < 4; ++c2)
        mycnt += (ss[c2] > CONF_T && __float_as_uint(ss[c2]) >= loKey) ? 1u : 0u;
    }
    u32 inc = mycnt;
#pragma unroll
    for (int off = 1; off < 64; off <<= 1) {
      u32 y = __shfl_up(inc, off);
      if (lane >= off) inc += y;
    }                                   // wave-inclusive scan
    if (lane == 63) wtot[wv] = inc;
    __syncthreads();
    u32 wbase = 0;
    for (int w = 0; w < wv; ++w) wbase += wtot[w];
    u32 pos = wbase + (inc - mycnt);    // block-exclusive offset
    if (t == TPB_N - 1) sh_nc = wbase + inc;
#pragma unroll
    for (int k = 0; k < 9; ++k) {
      int i = t + k * TPB_N;
      float ss[4] = {v[k].x, v[k].y, v[k].z, v[k].w};
#pragma unroll
      for (int c2 = 0; c2 < 4; ++c2) {
        float s = ss[c2];
        u32 key = __float_as_uint(s);
        if (s > CONF_T && key >= loKey) {
          if (pos < (u32)POOL)
            pool[pos] = ((u64)key << 32) | (u64)(0xFFFFFFFFu - (u32)(i * 4 + c2));
          ++pos;
        }
      }
    }
  }
  __syncthreads();

  // ---- rank-by-counting: composite keys unique -> rank = #{keys > mine} ----
  // pool pre-zeroed, so b128 reads past nc compare against 0 (harmless).
  u32 nc = sh_nc < (u32)POOL ? sh_nc : (u32)POOL;
  const bool dual = nc > (u32)TPB_N;    // block-uniform; rare (lvl-2 exit >512)
  u64 my0 = (t < (int)nc) ? pool[t] : 0ULL;
  u64 my1 = (dual && t + TPB_N < (int)nc) ? pool[t + TPB_N] : 0ULL;
  u32 r0 = 0, r1 = 0;
  if ((u32)(t & ~63) < nc) {            // whole waves past nc skip the loop
    if (!dual) {
#pragma unroll 4
      for (u32 k = 0; k < nc; k += 2) { // 2 keys per ds_read_b128
        ulonglong2 pk = *(const ulonglong2*)&pool[k];
        r0 += (pk.x > my0) ? 1u : 0u;
        r0 += (pk.y > my0) ? 1u : 0u;
      }
    } else {
#pragma unroll 4
      for (u32 k = 0; k < nc; k += 2) {
        ulonglong2 pk = *(const ulonglong2*)&pool[k];
        r0 += (pk.x > my0) ? 1u : 0u;
        r0 += (pk.y > my0) ? 1u : 0u;
        r1 += (pk.x > my1) ? 1u : 0u;
        r1 += (pk.y > my1) ? 1u : 0u;
      }
    }
  }
  if (my0 != 0ULL && r0 < (u32)K_) spool[r0] = my0;
  if (dual && my1 != 0ULL && r1 < (u32)K_) spool[r1] = my1;
  __syncthreads();
  // spool[0..199] == exact top_k (desc score, ties by ascending index)

  // ---- decode boxes for top-200; idle threads 256+ zero rowmask ----
  float scv = 0.f;
  if (t < K_) {
    float x1 = 0.f, y1 = 0.f, x2 = 0.f, y2 = 0.f, area = 0.f;
    u64 e = spool[t];
    u32 kb = (u32)(e >> 32);
    if (kb != 0u) {
      scv = __uint_as_float(kb);
      u32 idx = 0xFFFFFFFFu - (u32)(e & 0xFFFFFFFFu);
      int nn = (idx < (u32)N_) ? (int)idx : (int)(idx - N_);
      float4 l = (idx < (u32)N_) ? loc1[(size_t)bimg * N_ + nn]
                                 : loc2[(size_t)bimg * N_ + nn];
      float4 d = dbox[nn];
      float cx = d.x + l.x * 0.1f * d.z;
      float cy = d.y + l.y * 0.1f * d.w;
      float w = d.z * __expf(l.z * 0.2f);
      float h = d.w * __expf(l.w * 0.2f);
      x1 = cx - w * 0.5f; y1 = cy - h * 0.5f;
      x2 = cx + w * 0.5f; y2 = cy + h * 0.5f;
      if (idx >= (u32)N_) {   // horizontal flip of second (TTA) view
        float tmp = 1.0f - x2; x2 = 1.0f - x1; x1 = tmp;
      }
      area = (x2 - x1) * (y2 - y1);
    }
    bb[t] = make_float4(x1, y1, x2, y2);
    bar[t] = area;
  } else if (t >= 256) {
    for (int i = t - 256; i < 4 * K_; i += 256) ((u64*)rowmask)[i] = 0ULL;
  }
  {
    bool myvalid = (t < K_) && (scv > CONF_T);
    u64 bal = __ballot(myvalid);
    if (lane == 0 && wv < 4) validmask[wv] = bal;
  }
  __syncthreads();

  // ---- triangle IoU: row j, cols j+1..199, split in half across 400 threads ----
  if (t < 2 * K_) {
    const int j = (t < K_) ? t : (t - K_);
    const int h = (t < K_) ? 0 : 1;
    const int L = K_ - 1 - j;             // #cols after j
    const int half = (L + 1) >> 1;
    const int s0c = j + 1 + (h ? half : 0);
    const int e0c = h ? K_ : (j + 1 + half);
    if (s0c < e0c) {
      float4 mb = bb[j];
      float ma = bar[j];
      for (int w = (s0c >> 6); w <= ((e0c - 1) >> 6); ++w) {
        int ka = (w << 6) > s0c ? (w << 6) : s0c;
        int kb2 = ((w + 1) << 6) < e0c ? ((w + 1) << 6) : e0c;
        u64 m = 0ULL;
        for (int k2 = ka; k2 < kb2; ++k2) {
          float4 obx = bb[k2];
          float ox1 = fmaxf(mb.x, obx.x);
          float oy1 = fmaxf(mb.y, obx.y);
          float ox2 = fminf(mb.z, obx.z);
          float oy2 = fminf(mb.w, obx.w);
          float inter = fmaxf(ox2 - ox1, 0.f) * fmaxf(oy2 - oy1, 0.f);
          float uni = ma + bar[k2] - inter;
          m |= (inter > NMS_T * uni) ? (1ULL << (k2 & 63)) : 0ULL;
        }
        if (m) atomicOr(&rowmask[j][w], m);
      }
    }
  }
  __syncthreads();
  // waves 1-7 are done; wave 0 finishes the block alone.

  // ---- static pipelined greedy scan, chunked by word (triangle: j>=64 never
  // touches word 0, etc.), then in-wave compact ----
  if (t < 64) {
    const u64 vv0 = validmask[0], vv1 = validmask[1];
    const u64 vv2 = validmask[2], vv3 = validmask[3];
    u64 s0 = 0, s1 = 0, s2 = 0, s3 = 0;
    u64 k0 = 0, k1 = 0, k2m = 0, k3 = 0;
#pragma unroll 8
    for (int j = 0; j < 64; ++j) {
      u64 q0 = rowmask[j][0], q1 = rowmask[j][1], q2 = rowmask[j][2], q3 = rowmask[j][3];
      u64 bit = 1ULL << j;
      if ((vv0 & bit) && !(s0 & bit)) { s0 |= q0; s1 |= q1; s2 |= q2; s3 |= q3; k0 |= bit; }
    }
#pragma unroll 8
    for (int j = 64; j < 128; ++j) {
      u64 q1 = rowmask[j][1], q2 = rowmask[j][2], q3 = rowmask[j][3];
      u64 bit = 1ULL << (j & 63);
      if ((vv1 & bit) && !(s1 & bit)) { s1 |= q1; s2 |= q2; s3 |= q3; k1 |= bit; }
    }
#pragma unroll 8
    for (int j = 128; j < 192; ++j) {
      u64 q2 = rowmask[j][2], q3 = rowmask[j][3];
      u64 bit = 1ULL << (j & 63);
      if ((vv2 & bit) && !(s2 & bit)) { s2 |= q2; s3 |= q3; k2m |= bit; }
    }
#pragma unroll
    for (int j = 192; j < K_; ++j) {
      u64 q3 = rowmask[j][3];
      u64 bit = 1ULL << (j & 63);
      if ((vv3 & bit) && !(s3 & bit)) { s3 |= q3; k3 |= bit; }
    }
    // ---- compact kept entries (lane-parallel within wave 0) ----
    const u32 n0 = (u32)__popcll(k0);
    const u32 n01 = n0 + (u32)__popcll(k1);
    const u32 n012 = n01 + (u32)__popcll(k2m);
    const u64 below = (1ULL << lane) - 1ULL;
#pragma unroll
    for (int w = 0; w < 4; ++w) {
      int j = (w << 6) + lane;
      if (j < K_) {
        u64 kw = (w == 0) ? k0 : (w == 1) ? k1 : (w == 2) ? k2m : k3;
        if ((kw >> lane) & 1ULL) {
          int pos2 = (int)__popcll(kw & below)
                  + (int)((w == 0) ? 0u : (w == 1) ? n0 : (w == 2) ? n01 : n012);
          u64 e = spool[j];
          float sc = __uint_as_float((u32)(e >> 32));
          float4 bx = bb[j];
          float* o = ob + (size_t)pos2 * 5;
          o[0] = sc; o[1] = bx.x; o[2] = bx.y; o[3] = bx.z; o[4] = bx.w;
        }
      }
    }
  }
}

extern "C" void kernel_launch(void* const* d_in, const int* in_sizes, int n_in,
                              void* d_out, int out_size, void* d_ws, size_t ws_size,
                              hipStream_t stream) {
  const float* loc1 = (const float*)d_in[0];
  const float* conf1 = (const float*)d_in[1];
  const float* loc2 = (const float*)d_in[2];
  const float* conf2 = (const float*)d_in[3];
  const float* dbox = (const float*)d_in[4];
  float* out = (float*)d_out;
  float* scores = (float*)d_ws;   // [B, NCLS, 2N] fp32 = 44.7 MB

  dim3 g1((N_ + TPB_S - 1) / TPB_S, B_, 2);
  softmax_kernel<<<g1, TPB_S, 0, stream>>>(conf1, conf2, scores);

  nms_kernel<<<B_ * NCLS, TPB_N, 0, stream>>>(
      scores, (const float4*)loc1, (const float4*)loc2, (const float4*)dbox, out);
}

// Round 13
// 141.759 us; speedup vs baseline: 1.5370x; 1.0632x over previous
//
#include <hip/hip_runtime.h>

#define B_ 32
#define N_ 8732
#define N2_ 17464
#define N4_ 4366      // N2_/4 exactly
#define C_ 21
#define NCLS 20
#define K_ 200
#define CONF_T 0.01f
#define NMS_T 0.45f
#define TPB_S 256
#define TPB_N 512
#define POOL 1024
#define RANKCAP 512   // refine-descent target (fallback refine path)
#define HB0 2048      // level-0 bins (shift 15)
#define HB 1024       // refine-level bins (shift 5 then 0)
#define BIN0 30791u   // 0x3C23D70B >> 15: bin offset for level 0

typedef unsigned long long u64;
typedef unsigned int u32;

// ---------------------------------------------------------------------------
// Kernel 1 (round-6 hardware-verified, unchanged): softmax over C=21.
// Coalesced float4->LDS staging, per-row compute in registers, DIRECT global
// dword stores per class plane. Grid: (ceil(N/256), B, 2 views).
// ---------------------------------------------------------------------------
__global__ __launch_bounds__(TPB_S) void softmax_kernel(
    const float* __restrict__ conf1, const float* __restrict__ conf2,
    float* __restrict__ scores)
{
  __shared__ float lds[TPB_S * C_];   // 21 KB
  const int t = threadIdx.x;
  const int tile = blockIdx.x * TPB_S;
  const int b = blockIdx.y;
  const int view = blockIdx.z;
  int cnt = N_ - tile; if (cnt > TPB_S) cnt = TPB_S;   // 256 or 28 (both %4==0)
  const float* conf = view ? conf2 : conf1;
  const float4* src = (const float4*)(conf + ((size_t)b * N_ + tile) * C_);  // 16B-aligned
  float4* l4 = (float4*)lds;
  const int n4 = (cnt * C_) >> 2;
  for (int i = t; i < n4; i += TPB_S) l4[i] = src[i];
  __syncthreads();
  if (t < cnt) {
    float x[C_];
#pragma unroll
    for (int i = 0; i < C_; ++i) x[i] = lds[t * C_ + i];  // stride-21: 2-way, free
    float m = x[0];
#pragma unroll
    for (int i = 1; i < C_; ++i) m = fmaxf(m, x[i]);
    float e[C_];
    float sum = 0.0f;
#pragma unroll
    for (int i = 0; i < C_; ++i) { e[i] = __expf(x[i] - m); sum += e[i]; }
    float inv = 1.0f / sum;   // one IEEE div, not 20
    float* o = scores + ((size_t)b * NCLS) * N2_ + (size_t)view * N_ + (tile + t);
#pragma unroll
    for (int c = 1; c < C_; ++c) { *o = e[c] * inv; o += N2_; }
  }
}

// ---------------------------------------------------------------------------
// Kernel 2: per-(image,class), round-11 verified structure with ONE change:
// the triangle-IoU phase uses WORD-ALIGNED tasks. Task (w,j) computes
// rowmask[j][w] over cols [w*64, min(w*64+64,200)) ∩ (j,199]. 580 tasks,
// grouped by w (w0:j0-62 | w1:j0-126 | w2:j0-190 | w3:j0-198), so a wave's
// lanes iterate the SAME k2 -> bb[k2]/bar[k2] reads are same-address
// broadcasts (conflict-free) instead of per-lane scattered b128 reads
// (~8-way bank serialization). Single writer per word -> plain store, no
// atomicOr. Per-(j,k2) pair computed exactly once, same arithmetic ->
// bit-identical output. One 512-thread block per (b, c); grid 640.
// ---------------------------------------------------------------------------
__global__ __launch_bounds__(TPB_N, 2) void nms_kernel(
    const float* __restrict__ scores,
    const float4* __restrict__ loc1,
    const float4* __restrict__ loc2,
    const float4* __restrict__ dbox,
    float* __restrict__ out)
{
  const int t = threadIdx.x;
  const int lane = t & 63;
  const int wv = t >> 6;
  const int bimg = blockIdx.x / NCLS;
  const int cls = 1 + (blockIdx.x % NCLS);
  const float4* sc4 = (const float4*)(scores + ((size_t)bimg * NCLS + (cls - 1)) * N2_);
  float* ob = out + ((size_t)bimg * C_ + cls) * K_ * 5;

  __shared__ u32 hist[HB0];              // 8 KB (L0: 2048 @shift15; refine: first 1024)
  __shared__ u64 pool[POOL] __attribute__((aligned(16)));  // 8 KB, pre-zeroed
  __shared__ u64 spool[256];             // 2 KB, rank-ordered top-200
  __shared__ float4 bb[K_];              // 3.2 KB
  __shared__ float bar[K_];
  __shared__ u64 rowmask[K_][4];         // 6.4 KB (triangle: row j has cols>j)
  __shared__ u64 validmask[4];
  __shared__ u32 wtot[8];
  __shared__ u32 sh_sel, sh_Sb, sh_Sn, sh_nc, sh_total;

  // ---- fused output zeroing (replaces hipMemsetAsync) ----
  {
    const float4 z4 = make_float4(0.f, 0.f, 0.f, 0.f);
    if (t < 250) ((float4*)ob)[t] = z4;                      // own (b,cls) slice
    if (cls == 1 && t >= 256 && t < 506)                     // background class 0
      ((float4*)(out + (size_t)bimg * C_ * K_ * 5))[t - 256] = z4;
  }

  // ---- load this (b,c)'s 17464 scores into registers: the ONLY global pass ----
  float4 v[9];
#pragma unroll
  for (int k = 0; k < 9; ++k) {
    int i = t + k * TPB_N;
    v[k] = (i < N4_) ? sc4[i] : make_float4(0.f, 0.f, 0.f, 0.f);
  }

  // ---- zero L0 hist (2048) + pool + spool ----
  hist[t] = 0u; hist[t + 512] = 0u; hist[t + 1024] = 0u; hist[t + 1536] = 0u;
  pool[t] = 0ULL; pool[t + TPB_N] = 0ULL;
  if (t < 256) spool[t] = 0ULL;
  __syncthreads();

  // ---- level 0: 2048-bin histogram at shift 15 ----
  // valid keys 0x3C23D70B..0x3F800000 -> (key>>15)-30791 in [0,1721]
#pragma unroll
  for (int k = 0; k < 9; ++k) {
    float ss[4] = {v[k].x, v[k].y, v[k].z, v[k].w};
#pragma unroll
    for (int c2 = 0; c2 < 4; ++c2) {
      float s = ss[c2];
      if (s > CONF_T)
        atomicAdd(&hist[(__float_as_uint(s) >> 15) - BIN0], 1u);
    }
  }
  __syncthreads();

  // ---- suffix sums over 2048 bins + FUSED bin select ----
  // Thread t owns bins 4t..4t+3 with suffix sums S0..S3; S4 = after_me is
  // the suffix of bin 4t+4. Every adjacent pair (h,h+1) checked inline.
  {
    u32 c0 = hist[4 * t + 0], c1 = hist[4 * t + 1];
    u32 c2b = hist[4 * t + 2], c3 = hist[4 * t + 3];
    u32 T = c0 + c1 + c2b + c3;
    u32 x = T;
#pragma unroll
    for (int off = 1; off < 64; off <<= 1) {
      u32 y = __shfl_down(x, off);
      if (lane + off < 64) x += y;
    }                                   // x = suffix-incl sum of thread totals in wave
    if (lane == 0) wtot[wv] = x;
    __syncthreads();
    u32 wafter = 0;
    for (int w = wv + 1; w < 8; ++w) wafter += wtot[w];
    u32 after_me = (x - T) + wafter;    // totals of threads strictly after t
    u32 S4 = after_me;
    u32 S3 = c3 + S4, S2 = c2b + S3, S1 = c1 + S2, S0 = c0 + S1;
    if (t == 0) sh_total = S0;          // total valid count
    if (S0 >= (u32)K_ && S1 < (u32)K_) { sh_sel = 4u * t + 0u; sh_Sb = S0; sh_Sn = S1; }
    if (S1 >= (u32)K_ && S2 < (u32)K_) { sh_sel = 4u * t + 1u; sh_Sb = S1; sh_Sn = S2; }
    if (S2 >= (u32)K_ && S3 < (u32)K_) { sh_sel = 4u * t + 2u; sh_Sb = S2; sh_Sn = S3; }
    if (S3 >= (u32)K_ && S4 < (u32)K_) { sh_sel = 4u * t + 3u; sh_Sb = S3; sh_Sn = S4; }
  }
  __syncthreads();

  u32 loKey, prefix = 0, Gacc = 0;
  bool needMore = false;
  {
    u32 total = sh_total;               // block-uniform
    if (total < (u32)K_) {
      loKey = 1u;                       // undershoot: take all valid (<200)
    } else {
      prefix = sh_sel + BIN0;           // real key>>15 value
      loKey = prefix << 15;
      Gacc = sh_Sn;
      needMore = sh_Sb > (u32)RANKCAP;  // rare: one 32768-key window holding >312
    }
  }

  // ---- refine levels (rare): shift 5 (1024 bins) then shift 0 (32 bins) ----
  for (int lvl = 1; lvl <= 2 && needMore; ++lvl) {
    const int shift = (lvl == 1) ? 5 : 0;
    const int mshift = (lvl == 1) ? 15 : 5;
    const u32 bmask = (lvl == 1) ? 1023u : 31u;
    for (int h = t; h < HB; h += TPB_N) hist[h] = 0u;
    __syncthreads();
#pragma unroll
    for (int k = 0; k < 9; ++k) {
      float ss[4] = {v[k].x, v[k].y, v[k].z, v[k].w};
#pragma unroll
      for (int c2 = 0; c2 < 4; ++c2) {
        float s = ss[c2];
        if (s > CONF_T) {
          u32 key = __float_as_uint(s);
          if ((key >> mshift) == prefix)
            atomicAdd(&hist[(key >> shift) & bmask], 1u);
        }
      }
    }
    __syncthreads();
    // suffix sums over 1024 bins: 2 bins/thread + wave scan
    u32 c0 = hist[2 * t], c1 = hist[2 * t + 1];
    u32 T = c0 + c1;
    u32 x = T;
#pragma unroll
    for (int off = 1; off < 64; off <<= 1) {
      u32 y = __shfl_down(x, off);
      if (lane + off < 64) x += y;
    }
    if (lane == 0) wtot[wv] = x;
    __syncthreads();
    u32 wafter = 0;
    for (int w = wv + 1; w < 8; ++w) wafter += wtot[w];
    u32 after_me = (x - T) + wafter;
    u32 S2 = after_me;
    u32 S1 = c1 + S2, S0 = c0 + S1;
    u32 need = (u32)K_ - Gacc;
    if (S0 >= need && S1 < need) { sh_sel = 2u * t + 0u; sh_Sb = S0; sh_Sn = S1; }
    if (S1 >= need && S2 < need) { sh_sel = 2u * t + 1u; sh_Sb = S1; sh_Sn = S2; }
    __syncthreads();
    prefix = (prefix << ((lvl == 1) ? 10 : 5)) | sh_sel;
    u32 candTotal = Gacc + sh_Sb;
    Gacc += sh_Sn;
    loKey = prefix << shift;
    needMore = (candTotal > (u32)RANKCAP) && (lvl < 2);
  }

  // ---- collect: count -> block scan -> per-thread sequential writes ----
  // (pool order is irrelevant: keys unique -> rank-by-counting invariant)
  {
    u32 mycnt = 0;
#pragma unroll
    for (int k = 0; k < 9; ++k) {
      float ss[4] = {v[k].x, v[k].y, v[k].z, v[k].w};
#pragma unroll
      for (int c2 = 0; c2 < 4; ++c2)
        mycnt += (ss[c2] > CONF_T && __float_as_uint(ss[c2]) >= loKey) ? 1u : 0u;
    }
    u32 inc = mycnt;
#pragma unroll
    for (int off = 1; off < 64; off <<= 1) {
      u32 y = __shfl_up(inc, off);
      if (lane >= off) inc += y;
    }                                   // wave-inclusive scan
    if (lane == 63) wtot[wv] = inc;
    __syncthreads();
    u32 wbase = 0;
    for (int w = 0; w < wv; ++w) wbase += wtot[w];
    u32 pos = wbase + (inc - mycnt);    // block-exclusive offset
    if (t == TPB_N - 1) sh_nc = wbase + inc;
#pragma unroll
    for (int k = 0; k < 9; ++k) {
      int i = t + k * TPB_N;
      float ss[4] = {v[k].x, v[k].y, v[k].z, v[k].w};
#pragma unroll
      for (int c2 = 0; c2 < 4; ++c2) {
        float s = ss[c2];
        u32 key = __float_as_uint(s);
        if (s > CONF_T && key >= loKey) {
          if (pos < (u32)POOL)
            pool[pos] = ((u64)key << 32) | (u64)(0xFFFFFFFFu - (u32)(i * 4 + c2));
          ++pos;
        }
      }
    }
  }
  __syncthreads();

  // ---- rank-by-counting: composite keys unique -> rank = #{keys > mine} ----
  // pool pre-zeroed, so b128 reads past nc compare against 0 (harmless).
  u32 nc = sh_nc < (u32)POOL ? sh_nc : (u32)POOL;
  const bool dual = nc > (u32)TPB_N;    // block-uniform; rare (lvl-2 exit >512)
  u64 my0 = (t < (int)nc) ? pool[t] : 0ULL;
  u64 my1 = (dual && t + TPB_N < (int)nc) ? pool[t + TPB_N] : 0ULL;
  u32 r0 = 0, r1 = 0;
  if ((u32)(t & ~63) < nc) {            // whole waves past nc skip the loop
    if (!dual) {
#pragma unroll 4
      for (u32 k = 0; k < nc; k += 2) { // 2 keys per ds_read_b128
        ulonglong2 pk = *(const ulonglong2*)&pool[k];
        r0 += (pk.x > my0) ? 1u : 0u;
        r0 += (pk.y > my0) ? 1u : 0u;
      }
    } else {
#pragma unroll 4
      for (u32 k = 0; k < nc; k += 2) {
        ulonglong2 pk = *(const ulonglong2*)&pool[k];
        r0 += (pk.x > my0) ? 1u : 0u;
        r0 += (pk.y > my0) ? 1u : 0u;
        r1 += (pk.x > my1) ? 1u : 0u;
        r1 += (pk.y > my1) ? 1u : 0u;
      }
    }
  }
  if (my0 != 0ULL && r0 < (u32)K_) spool[r0] = my0;
  if (dual && my1 != 0ULL && r1 < (u32)K_) spool[r1] = my1;
  __syncthreads();
  // spool[0..199] == exact top_k (desc score, ties by ascending index)

  // ---- decode boxes for top-200; idle threads 256+ zero rowmask ----
  float scv = 0.f;
  if (t < K_) {
    float x1 = 0.f, y1 = 0.f, x2 = 0.f, y2 = 0.f, area = 0.f;
    u64 e = spool[t];
    u32 kb = (u32)(e >> 32);
    if (kb != 0u) {
      scv = __uint_as_float(kb);
      u32 idx = 0xFFFFFFFFu - (u32)(e & 0xFFFFFFFFu);
      int nn = (idx < (u32)N_) ? (int)idx : (int)(idx - N_);
      float4 l = (idx < (u32)N_) ? loc1[(size_t)bimg * N_ + nn]
                                 : loc2[(size_t)bimg * N_ + nn];
      float4 d = dbox[nn];
      float cx = d.x + l.x * 0.1f * d.z;
      float cy = d.y + l.y * 0.1f * d.w;
      float w = d.z * __expf(l.z * 0.2f);
      float h = d.w * __expf(l.w * 0.2f);
      x1 = cx - w * 0.5f; y1 = cy - h * 0.5f;
      x2 = cx + w * 0.5f; y2 = cy + h * 0.5f;
      if (idx >= (u32)N_) {   // horizontal flip of second (TTA) view
        float tmp = 1.0f - x2; x2 = 1.0f - x1; x1 = tmp;
      }
      area = (x2 - x1) * (y2 - y1);
    }
    bb[t] = make_float4(x1, y1, x2, y2);
    bar[t] = area;
  } else if (t >= 256) {
    for (int i = t - 256; i < 4 * K_; i += 256) ((u64*)rowmask)[i] = 0ULL;
  }
  {
    bool myvalid = (t < K_) && (scv > CONF_T);
    u64 bal = __ballot(myvalid);
    if (lane == 0 && wv < 4) validmask[wv] = bal;
  }
  __syncthreads();

  // ---- triangle IoU, word-aligned tasks (580): lanes iterate the SAME k2
  // -> bb/bar reads broadcast; one writer per word -> plain store ----
  {
#pragma unroll
    for (int rep = 0; rep < 2; ++rep) {
      const int id = t + rep * TPB_N;
      if (id < 580) {
        int w, j;
        if (id < 63)       { w = 0; j = id; }
        else if (id < 190) { w = 1; j = id - 63; }
        else if (id < 381) { w = 2; j = id - 190; }
        else               { w = 3; j = id - 381; }
        const float4 mb = bb[j];
        const float ma = bar[j];
        const int k0c = w << 6;
        const int ke = (k0c + 64 < K_) ? (k0c + 64) : K_;
        u64 m = 0ULL;
        for (int k2 = k0c; k2 < ke; ++k2) {
          float4 obx = bb[k2];
          float ox1 = fmaxf(mb.x, obx.x);
          float oy1 = fmaxf(mb.y, obx.y);
          float ox2 = fminf(mb.z, obx.z);
          float oy2 = fminf(mb.w, obx.w);
          float inter = fmaxf(ox2 - ox1, 0.f) * fmaxf(oy2 - oy1, 0.f);
          float uni = ma + bar[k2] - inter;
          u64 bit = ((inter > NMS_T * uni) && (k2 > j)) ? 1ULL : 0ULL;
          m |= bit << (k2 & 63);
        }
        rowmask[j][w] = m;   // words fully below the diagonal stay zeroed
      }
    }
  }
  __syncthreads();
  // waves 1-7 are done; wave 0 finishes the block alone.

  // ---- static pipelined greedy scan, chunked by word (triangle: j>=64 never
  // touches word 0, etc.), then in-wave compact ----
  if (t < 64) {
    const u64 vv0 = validmask[0], vv1 = validmask[1];
    const u64 vv2 = validmask[2], vv3 = validmask[3];
    u64 s0 = 0, s1 = 0, s2 = 0, s3 = 0;
    u64 k0 = 0, k1 = 0, k2m = 0, k3 = 0;
#pragma unroll 8
    for (int j = 0; j < 64; ++j) {
      u64 q0 = rowmask[j][0], q1 = rowmask[j][1], q2 = rowmask[j][2], q3 = rowmask[j][3];
      u64 bit = 1ULL << j;
      if ((vv0 & bit) && !(s0 & bit)) { s0 |= q0; s1 |= q1; s2 |= q2; s3 |= q3; k0 |= bit; }
    }
#pragma unroll 8
    for (int j = 64; j < 128; ++j) {
      u64 q1 = rowmask[j][1], q2 = rowmask[j][2], q3 = rowmask[j][3];
      u64 bit = 1ULL << (j & 63);
      if ((vv1 & bit) && !(s1 & bit)) { s1 |= q1; s2 |= q2; s3 |= q3; k1 |= bit; }
    }
#pragma unroll 8
    for (int j = 128; j < 192; ++j) {
      u64 q2 = rowmask[j][2], q3 = rowmask[j][3];
      u64 bit = 1ULL << (j & 63);
      if ((vv2 & bit) && !(s2 & bit)) { s2 |= q2; s3 |= q3; k2m |= bit; }
    }
#pragma unroll
    for (int j = 192; j < K_; ++j) {
      u64 q3 = rowmask[j][3];
      u64 bit = 1ULL << (j & 63);
      if ((vv3 & bit) && !(s3 & bit)) { s3 |= q3; k3 |= bit; }
    }
    // ---- compact kept entries (lane-parallel within wave 0) ----
    const u32 n0 = (u32)__popcll(k0);
    const u32 n01 = n0 + (u32)__popcll(k1);
    const u32 n012 = n01 + (u32)__popcll(k2m);
    const u64 below = (1ULL << lane) - 1ULL;
#pragma unroll
    for (int w = 0; w < 4; ++w) {
      int j = (w << 6) + lane;
      if (j < K_) {
        u64 kw = (w == 0) ? k0 : (w == 1) ? k1 : (w == 2) ? k2m : k3;
        if ((kw >> lane) & 1ULL) {
          int pos2 = (int)__popcll(kw & below)
                  + (int)((w == 0) ? 0u : (w == 1) ? n0 : (w == 2) ? n01 : n012);
          u64 e = spool[j];
          float sc = __uint_as_float((u32)(e >> 32));
          float4 bx = bb[j];
          float* o = ob + (size_t)pos2 * 5;
          o[0] = sc; o[1] = bx.x; o[2] = bx.y; o[3] = bx.z; o[4] = bx.w;
        }
      }
    }
  }
}

extern "C" void kernel_launch(void* const* d_in, const int* in_sizes, int n_in,
                              void* d_out, int out_size, void* d_ws, size_t ws_size,
                              hipStream_t stream) {
  const float* loc1 = (const float*)d_in[0];
  const float* conf1 = (const float*)d_in[1];
  const float* loc2 = (const float*)d_in[2];
  const float* conf2 = (const float*)d_in[3];
  const float* dbox = (const float*)d_in[4];
  float* out = (float*)d_out;
  float* scores = (float*)d_ws;   // [B, NCLS, 2N] fp32 = 44.7 MB

  dim3 g1((N_ + TPB_S - 1) / TPB_S, B_, 2);
  softmax_kernel<<<g1, TPB_S, 0, stream>>>(conf1, conf2, scores);

  nms_kernel<<<B_ * NCLS, TPB_N, 0, stream>>>(
      scores, (const float4*)loc1, (const float4*)loc2, (const float4*)dbox, out);
}